// Round 10
// baseline (319.918 us; speedup 1.0000x reference)
//
#include <hip/hip_runtime.h>
#include <hip/hip_cooperative_groups.h>
#include <math.h>

namespace cg = cooperative_groups;

#define NN 50000
#define NE 800000
#define LEAKY 0.2f
#define NT 26              // 26 column tiles of 16 (416 cols, 400 real)
#define CAP 96             // padded CSR slots/node
#define NBT (8 * NT * 64)  // Btf fragment count
#define NB1 391            // S1 blocks (2048 edges each; last 1280)
#define S1E 2048
#define NBUCK 196          // coarse buckets of 256 nodes
#define EBMAX 5120         // S2 per-bucket edge buffer
#define GRID_BLKS 1024     // cooperative grid: 4 blocks/CU x 256 CUs
#define PA_ITEMS (55 + NB1)      // 446
#define GEMM_USED 1564
#define PB_ITEMS (196 + GEMM_USED)   // 1760
#define PC_ITEMS 3125

typedef short bf16x8 __attribute__((ext_vector_type(8)));
typedef float f32x4 __attribute__((ext_vector_type(4)));
typedef float f32x2 __attribute__((ext_vector_type(2)));

__device__ __forceinline__ unsigned short f2bf(float f) {
  unsigned u = __float_as_uint(f);
  u += 0x7fffu + ((u >> 16) & 1u);
  return (unsigned short)(u >> 16);
}
__device__ __forceinline__ float leaky(float v) { return v > 0.0f ? v : LEAKY * v; }
__device__ __forceinline__ float rlf(float v, int l) {
  return __uint_as_float(__builtin_amdgcn_readlane(__float_as_uint(v), l));
}
__device__ __forceinline__ int rli(int v, int l) {
  return __builtin_amdgcn_readlane(v, l);
}

__device__ __forceinline__ bf16x8 cvt8(float4 fa, float4 fb) {
  unsigned r0, r1, r2, r3;
  asm("v_cvt_pk_bf16_f32 %0, %1, %2" : "=v"(r0) : "v"(fa.x), "v"(fa.y));
  asm("v_cvt_pk_bf16_f32 %0, %1, %2" : "=v"(r1) : "v"(fa.z), "v"(fa.w));
  asm("v_cvt_pk_bf16_f32 %0, %1, %2" : "=v"(r2) : "v"(fb.x), "v"(fb.y));
  asm("v_cvt_pk_bf16_f32 %0, %1, %2" : "=v"(r3) : "v"(fb.z), "v"(fb.w));
  union { uint4 u; bf16x8 v; } c;
  c.u = make_uint4(r0, r1, r2, r3);
  return c.v;
}

#if defined(__has_builtin)
#if __has_builtin(__builtin_amdgcn_cvt_pk_f32_fp8) && \
    __has_builtin(__builtin_amdgcn_cvt_pk_fp8_f32) && \
    __has_builtin(__builtin_amdgcn_cvt_f32_fp8)
#define FP8_HW 1
#endif
#endif

#ifdef FP8_HW
__device__ __forceinline__ unsigned char f2fp8(float v) {
  return (unsigned char)(__builtin_amdgcn_cvt_pk_fp8_f32(v, v, 0u, false) & 0xFF);
}
__device__ __forceinline__ f32x2 fp8x2_lo(unsigned int v) {
  return __builtin_amdgcn_cvt_pk_f32_fp8(v, false);
}
__device__ __forceinline__ f32x2 fp8x2_hi(unsigned int v) {
  return __builtin_amdgcn_cvt_pk_f32_fp8(v, true);
}
__device__ __forceinline__ float fp8one(unsigned int v) {
  return __builtin_amdgcn_cvt_f32_fp8(v, 0);
}
#else
__device__ __forceinline__ unsigned char f2fp8(float f) {
  unsigned u = __float_as_uint(f);
  unsigned s = (u >> 31) << 7;
  unsigned a = u & 0x7FFFFFFFu;
  if (a >= 0x43E00000u) return (unsigned char)(s | 0x7E);
  if (a < 0x3C800000u) {
    float m = __uint_as_float(a) * 512.0f;
    int q = (int)(m + 0.5f); if (q > 7) q = 7;
    return (unsigned char)(s | q);
  }
  a += 0x7FFFFu + ((a >> 20) & 1);
  unsigned e = ((a >> 23) & 0xFF) - 120;
  if (e > 15) return (unsigned char)(s | 0x7E);
  return (unsigned char)(s | (e << 3) | ((a >> 20) & 7));
}
__device__ __forceinline__ float fp8dec1(unsigned b) {
  unsigned s = (b & 0x80u) << 24;
  unsigned em = b & 0x7Fu;
  unsigned e4 = em >> 3, m3 = em & 7;
  float v = e4 ? __uint_as_float(((e4 + 120) << 23) | (m3 << 20))
               : (float)m3 * 0.001953125f;
  return __uint_as_float(__float_as_uint(v) ^ s);
}
__device__ __forceinline__ f32x2 fp8x2_lo(unsigned int v) {
  f32x2 r; r[0] = fp8dec1(v & 0xFF); r[1] = fp8dec1((v >> 8) & 0xFF); return r;
}
__device__ __forceinline__ f32x2 fp8x2_hi(unsigned int v) {
  f32x2 r; r[0] = fp8dec1((v >> 16) & 0xFF); r[1] = fp8dec1((v >> 24) & 0xFF); return r;
}
__device__ __forceinline__ float fp8one(unsigned int v) { return fp8dec1(v & 0xFF); }
#endif

// Panel columns (416 = 26 tiles of 16): see earlier rounds for map.
__device__ __forceinline__ float dot64v(const float* __restrict__ w,
                                        const float* __restrict__ a) {
  float4 p0 = {0.f, 0.f, 0.f, 0.f};
#pragma unroll
  for (int o = 0; o < 64; o += 4) {
    float4 wv = *(const float4*)(w + o);
    float4 av = *(const float4*)(a + o);
    p0.x += wv.x * av.x; p0.y += wv.y * av.y;
    p0.z += wv.z * av.z; p0.w += wv.w * av.w;
  }
  return (p0.x + p0.y) + (p0.z + p0.w);
}
__device__ __forceinline__ float panel_w(int col, int k,
    const float* W_gat, const float* gate_m_W, const float* merge_W,
    const float* gate_fn_W, const float* attn_l, const float* attn_r) {
  if (col < 256)      return W_gat[k * 256 + (col & 3) * 64 + (col >> 2)];
  else if (col < 320) return gate_m_W[k * 64 + (col - 256)];
  else if (col < 384) return merge_W[k * 64 + (col - 320)];
  else if (col < 388) return gate_fn_W[k * 4 + (col - 384)];
  else if (col < 392) return gate_fn_W[(320 + k) * 4 + (col - 388)];
  else if (col < 396) {
    int h = col - 392;
    return dot64v(W_gat + k * 256 + h * 64, attn_l + h * 64);
  } else if (col < 400) {
    int h = col - 396;
    return dot64v(W_gat + k * 256 + h * 64, attn_r + h * 64);
  }
  return 0.0f;
}

union FusedLDS {
  unsigned short ldsB[2][13][64][8];     // 26624 B (gemm)
  struct {
    int hist[NBUCK]; int cntb[NBUCK]; int pfx[NBUCK]; int sc[256];
    unsigned staged_l[S1E];
  } s1;                                  // 11568 B
  struct {
    unsigned eb[EBMAX]; int cnt2[256]; int sc[256];
  } s2;                                  // 22528 B
  struct {
    float WzT[4][64]; float pbuf[4][16][4]; unsigned short gLDS[16][72];
  } nd;                                  // 4352 B
};

// ---------------- Phase A item: weight prep / sentinels / S1 sort ----------------
__device__ void phaseA_item(int it, int tid, FusedLDS& L,
    const float* __restrict__ W_gat, const float* __restrict__ gate_m_W,
    const float* __restrict__ merge_W, const float* __restrict__ gate_fn_W,
    const float* __restrict__ attn_l, const float* __restrict__ attn_r,
    unsigned short* __restrict__ Btf, unsigned short* __restrict__ mWf,
    unsigned char* __restrict__ zq, float* __restrict__ epay,
    unsigned char* __restrict__ featq,
    const int* __restrict__ src, const int* __restrict__ dst,
    unsigned int* __restrict__ staged, unsigned short* __restrict__ bofs) {
  if (it < 54) {
    int idx = it * 256 + tid;
    if (idx < NBT) {
      int kq = idx / (NT * 64);
      int rem = idx - kq * (NT * 64);
      int t = rem >> 6, lane = rem & 63;
      int col = t * 16 + (lane & 15);
      int k = kq * 32 + (lane >> 4) * 8;
      unsigned short* o = Btf + (size_t)idx * 8;
#pragma unroll
      for (int i = 0; i < 8; ++i)
        o[i] = f2bf(panel_w(col, k + i, W_gat, gate_m_W, merge_W, gate_fn_W,
                            attn_l, attn_r));
    } else {
      int idx2 = idx - NBT;       // < 512
      int kq = idx2 >> 8;
      int rem = idx2 & 255;
      int t = rem >> 6, lane = rem & 63;
      int col = t * 16 + (lane & 15);
      int k = kq * 32 + ((lane >> 4) & 3) * 8;
      unsigned short* o = mWf + (size_t)idx2 * 8;
#pragma unroll
      for (int i = 0; i < 8; ++i)
        o[i] = f2bf(merge_W[(size_t)(256 + k + i) * 64 + col]);
    }
  } else if (it == 54) {
    if (tid < 64) zq[(size_t)NN * 64 + tid] = 0xFE;   // sentinel z = -448
    if (tid < 8) epay[(size_t)NN * 8 + tid] = 0.0f;   // sentinel el/u = 0
    featq[(size_t)NN * 256 + tid] = 0;                // sentinel feat = 0
  } else {
    // ---------------- S1 ----------------
    int s1b = it - 55;
    int e0 = s1b * S1E;
    int cntE = NE - e0; if (cntE > S1E) cntE = S1E;
    for (int i = tid; i < NBUCK; i += 256) { L.s1.hist[i] = 0; L.s1.cntb[i] = 0; }
    __syncthreads();
    int myn[8], mys[8];
#pragma unroll
    for (int j = 0; j < 8; ++j) {
      int li = j * 256 + tid;
      bool valid = li < cntE;
      myn[j] = valid ? dst[e0 + li] : -1;
      mys[j] = valid ? src[e0 + li] : 0;
      if (valid) atomicAdd(&L.s1.hist[myn[j] >> 8], 1);
    }
    __syncthreads();
    int v = (tid < NBUCK) ? L.s1.hist[tid] : 0;
    L.s1.sc[tid] = v; __syncthreads();
#pragma unroll
    for (int off = 1; off < 256; off <<= 1) {
      int t = (tid >= off) ? L.s1.sc[tid - off] : 0;
      __syncthreads();
      L.s1.sc[tid] += t;
      __syncthreads();
    }
    if (tid < NBUCK) L.s1.pfx[tid] = L.s1.sc[tid] - v;
    __syncthreads();
#pragma unroll
    for (int j = 0; j < 8; ++j) {
      if (myn[j] >= 0) {
        int bk = myn[j] >> 8;
        int p = L.s1.pfx[bk] + atomicAdd(&L.s1.cntb[bk], 1);
        L.s1.staged_l[p] = ((unsigned)mys[j] << 8) | (unsigned)(myn[j] & 255);
      }
    }
    __syncthreads();
    for (int i = tid; i < cntE; i += 256) staged[(size_t)e0 + i] = L.s1.staged_l[i];
    for (int i = tid; i < NBUCK + 1; i += 256)
      bofs[(size_t)s1b * (NBUCK + 1) + i] =
          (unsigned short)((i < NBUCK) ? L.s1.pfx[i] : cntE);
    __syncthreads();   // protect staged_l before next item reuses union
  }
}

// ---------------- Phase B item: S2 CSR placement / half-panel LDS gemm ----------------
__device__ void phaseB_item(int it, int tid, FusedLDS& L,
    const float* __restrict__ x, const unsigned short* __restrict__ Btf,
    const float* __restrict__ gate_m_b,
    unsigned char* __restrict__ featq, unsigned char* __restrict__ zq,
    float* __restrict__ xm, float* __restrict__ gx, float* __restrict__ epay,
    float* __restrict__ erv,
    const unsigned int* __restrict__ staged, const unsigned short* __restrict__ bofs,
    int* __restrict__ deg, unsigned short* __restrict__ csr_src) {
  if (it < 196) {
    // ---------------- S2 ----------------
    int bk = it;
    int nb0 = bk << 8;
    int mycnt[2], myofs[2];
#pragma unroll
    for (int k = 0; k < 2; ++k) {
      int bi = tid + k * 256;
      if (bi < NB1) {
        int o  = bofs[(size_t)bi * (NBUCK + 1) + bk];
        int n1 = bofs[(size_t)bi * (NBUCK + 1) + bk + 1];
        myofs[k] = o; mycnt[k] = n1 - o;
      } else { myofs[k] = 0; mycnt[k] = 0; }
    }
    int lsum = mycnt[0] + mycnt[1];
    L.s2.sc[tid] = lsum; __syncthreads();
#pragma unroll
    for (int off = 1; off < 256; off <<= 1) {
      int t = (tid >= off) ? L.s2.sc[tid - off] : 0;
      __syncthreads();
      L.s2.sc[tid] += t;
      __syncthreads();
    }
    int base = L.s2.sc[tid] - lsum;
    int Eb = L.s2.sc[255];
    if (Eb > EBMAX) Eb = EBMAX;
    int pos = base;
#pragma unroll
    for (int k = 0; k < 2; ++k) {
      int bi = tid + k * 256;
      for (int c = 0; c < mycnt[k]; ++c) {
        if (pos < EBMAX)
          L.s2.eb[pos] = staged[(size_t)bi * S1E + myofs[k] + c];
        ++pos;
      }
    }
    __syncthreads();
    L.s2.cnt2[tid] = 0;
    __syncthreads();
    for (int i = tid; i < Eb; i += 256) {
      unsigned v = L.s2.eb[i];
      int nl = v & 255;
      int p = atomicAdd(&L.s2.cnt2[nl], 1);       // LDS atomic
      if (p < CAP)
        csr_src[(size_t)(nb0 + nl) * CAP + p] = (unsigned short)(v >> 8);
    }
    __syncthreads();
    int n = nb0 + tid;
    if (n < NN) {
      int d = L.s2.cnt2[tid];
      deg[n] = d < CAP ? d : CAP;
    }
    __syncthreads();   // cnt2 reads done before union reuse
    return;
  }
  // ---------------- gemm (round-8 half-panel, LDS double-buffered B) ----------------
  int bq = it - 196;
  int rb = bq >> 1, ch = bq & 1;
  int lane = tid & 63, wave = tid >> 6;
  int m = lane & 15, kg = lane >> 4;
  int rowB = rb * 64;
  int t0 = ch * 13;
  int arow = rowB + wave * 16 + m;
  if (arow >= NN) arow = NN - 1;          // clamp (stores guarded below)
  const float* aP = x + (size_t)arow * 256 + kg * 8;

  f32x4 acc[13];
  f32x4 zero = {0.f, 0.f, 0.f, 0.f};
#pragma unroll
  for (int t = 0; t < 13; ++t) acc[t] = zero;

  for (int t = wave; t < 13; t += 4)
    __builtin_amdgcn_global_load_lds(
        (const __attribute__((address_space(1))) unsigned int*)
            (Btf + ((size_t)(t0 + t)) * 512 + lane * 8),
        (__attribute__((address_space(3))) unsigned int*)(&L.ldsB[0][t][0][0]),
        16, 0, 0);
  float4 fa = *(const float4*)aP;
  float4 fb = *(const float4*)(aP + 4);
  __syncthreads();

#pragma unroll 1
  for (int kq = 0; kq < 8; ++kq) {
    int cur = kq & 1;
    int kqn = kq < 7 ? kq + 1 : 7;
    float4 fa_n = *(const float4*)(aP + kqn * 32);
    float4 fb_n = *(const float4*)(aP + kqn * 32 + 4);
    if (kq < 7) {
      for (int t = wave; t < 13; t += 4)
        __builtin_amdgcn_global_load_lds(
            (const __attribute__((address_space(1))) unsigned int*)
                (Btf + ((size_t)(kq + 1) * NT + t0 + t) * 512 + lane * 8),
            (__attribute__((address_space(3))) unsigned int*)
                (&L.ldsB[cur ^ 1][t][0][0]),
            16, 0, 0);
    }
    bf16x8 a = cvt8(fa, fb);
#pragma unroll
    for (int t = 0; t < 13; ++t) {
      bf16x8 bfr = *(const bf16x8*)&L.ldsB[cur][t][lane][0];
      acc[t] = __builtin_amdgcn_mfma_f32_16x16x32_bf16(a, bfr, acc[t], 0, 0, 0);
    }
    fa = fa_n; fb = fb_n;
    __syncthreads();
  }

  if (ch == 0) {
#pragma unroll
    for (int r = 0; r < 4; ++r) {
      int row = rowB + wave * 16 + kg * 4 + r;
      if (row >= NN) continue;
#pragma unroll
      for (int t = 0; t < 13; ++t)
        featq[(size_t)row * 256 + t * 16 + m] = f2fp8(acc[t][r]);
    }
  } else {
#pragma unroll
    for (int r = 0; r < 4; ++r) {
      int row = rowB + wave * 16 + kg * 4 + r;
      if (row >= NN) continue;
#pragma unroll
      for (int t = 0; t < 3; ++t)            // tiles 13..15: feat cols 208+
        featq[(size_t)row * 256 + 208 + t * 16 + m] = f2fp8(acc[t][r]);
#pragma unroll
      for (int t = 3; t < 7; ++t) {          // tiles 16..19: z
        int cc = (t - 3) * 16 + m;
        zq[(size_t)row * 64 + cc] = f2fp8(acc[t][r] + gate_m_b[cc]);
      }
#pragma unroll
      for (int t = 7; t < 11; ++t)           // tiles 20..23: xm
        xm[(size_t)row * 64 + (t - 7) * 16 + m] = acc[t][r];
      float v = acc[11][r];                  // tile 24: gx | u | el | er
      if (m < 4)       gx[(size_t)row * 4 + m] = v;
      else if (m < 8)  epay[(size_t)row * 8 + (m - 4) * 2 + 1] = v;   // u
      else if (m < 12) epay[(size_t)row * 8 + (m - 8) * 2] = v;       // el
      else             erv[(size_t)row * 4 + (m - 12)] = v;           // er
    }
  }
}

// ---------------- Phase C item: node gather + gated merge ----------------
__device__ void phaseC_block(int nb, int tid, FusedLDS& L,
    const unsigned char* __restrict__ zq, const unsigned char* __restrict__ featq,
    const float* __restrict__ epay, const float* __restrict__ er,
    const float* __restrict__ gx,
    const int* __restrict__ deg, const unsigned short* __restrict__ csr_src,
    const float* __restrict__ gate_fn_W, const float* __restrict__ gate_fn_b,
    const unsigned short* __restrict__ mWf, const float* __restrict__ xm,
    const float* __restrict__ merge_b, float* __restrict__ out) {
  {
    int c = tid >> 2, h = tid & 3;
    L.nd.WzT[h][c] = gate_fn_W[(256 + c) * 4 + h];
  }
  __syncthreads();

  int lane = tid & 63, wave = tid >> 6;
  int hh = lane >> 4, le = lane & 15;
  int rowbase = nb * 16;
  int nodeBase = rowbase + wave * 4;
#pragma unroll 1
  for (int i = 0; i < 4; ++i) {
    int node = nodeBase + i;
    int dg = deg[node]; if (dg > CAP) dg = CAP;
    float gated = 0.0f;
    if (dg > 0) {
      int rs = node * CAP, re = rs + dg;
      float er_h = er[(size_t)node * 4 + hh];
      f32x2 A01 = {0.f, 0.f}, A23 = {0.f, 0.f};
      float psum = 0, usum = 0;
      float mz = -INFINITY;
      int jj = rs + le;
      int s_l = (jj < re) ? (int)csr_src[jj] : NN;   // NN = sentinel row
#pragma unroll 1
      for (int j0 = rs; j0 < re; j0 += 16) {
        int jn = j0 + 16 + le;
        int s_nx = (jn < re) ? (int)csr_src[jn] : NN;
        bool valid = (j0 + le) < re;
        float2 eu = *(const float2*)(epay + ((size_t)(unsigned)s_l << 3) + hh * 2);
        float p = valid ? __expf(leaky(eu.x + er_h)) : 0.0f;
        psum += p;
        usum += eu.y;                                // sentinel u == 0
        L.nd.pbuf[wave][le][hh] = p;                 // wave-synchronous broadcast
        unsigned int fvr[16];
        unsigned int zvr[16];
#pragma unroll
        for (int e2 = 0; e2 < 16; ++e2) {
          int s = rli(s_l, e2);                      // SGPR row id -> scalar base
          fvr[e2] = *(const unsigned int*)(featq + ((size_t)(unsigned)s << 8) + lane * 4);
        }
#pragma unroll
        for (int e2 = 0; e2 < 16; ++e2) {
          int s = rli(s_l, e2);
          zvr[e2] = zq[((size_t)(unsigned)s << 6) + lane];
        }
#pragma unroll
        for (int e2 = 0; e2 < 16; ++e2) {
          float4 pv = *(const float4*)L.nd.pbuf[wave][e2];  // uniform ds_read_b128
          f32x2 p01 = {pv.x, pv.y};
          f32x2 p23 = {pv.z, pv.w};
          A01 += p01 * fp8x2_lo(fvr[e2]);
          A23 += p23 * fp8x2_hi(fvr[e2]);
          mz = fmaxf(mz, fp8one(zvr[e2]));
        }
        s_l = s_nx;
      }
#pragma unroll
      for (int off = 1; off < 16; off <<= 1) {
        psum += __shfl_xor(psum, off, 64);
        usum += __shfl_xor(usum, off, 64);
      }
      float s0 = rlf(psum, 0),  s1 = rlf(psum, 16);
      float s2 = rlf(psum, 32), s3 = rlf(psum, 48);
      float su0 = rlf(usum, 0),  su1 = rlf(usum, 16);
      float su2 = rlf(usum, 32), su3 = rlf(usum, 48);

      float g[4];
#pragma unroll
      for (int h = 0; h < 4; ++h) {
        float t = mz * L.nd.WzT[h][lane];
#pragma unroll
        for (int off = 32; off; off >>= 1) t += __shfl_xor(t, off, 64);
        g[h] = t;
      }
      float inv_deg = 1.0f / (float)dg;
      float4 gx4 = *(const float4*)(gx + (size_t)node * 4);
      float g0 = 1.0f / (1.0f + __expf(-(g[0] + gx4.x + su0 * inv_deg + gate_fn_b[0])));
      float g1 = 1.0f / (1.0f + __expf(-(g[1] + gx4.y + su1 * inv_deg + gate_fn_b[1])));
      float g2 = 1.0f / (1.0f + __expf(-(g[2] + gx4.z + su2 * inv_deg + gate_fn_b[2])));
      float g3 = 1.0f / (1.0f + __expf(-(g[3] + gx4.w + su3 * inv_deg + gate_fn_b[3])));
      gated = 0.25f * (g0 * A01[0] / s0 + g1 * A01[1] / s1 +
                       g2 * A23[0] / s2 + g3 * A23[1] / s3);
    }
    L.nd.gLDS[wave * 4 + i][lane] = f2bf(gated);
  }
  __syncthreads();

  // fused merge: out[16 rows][64] = gated @ merge_W[256:] + xm + merge_b
  int m = lane & 15, kg = lane >> 4;
  f32x4 acc = {0.f, 0.f, 0.f, 0.f};
#pragma unroll
  for (int kq = 0; kq < 2; ++kq) {
    bf16x8 a = *(const bf16x8*)(&L.nd.gLDS[m][kq * 32 + kg * 8]);
    bf16x8 b = *(const bf16x8*)(mWf + (((size_t)kq * 4 + wave) * 64 + lane) * 8);
    acc = __builtin_amdgcn_mfma_f32_16x16x32_bf16(a, b, acc, 0, 0, 0);
  }
  int c = wave * 16 + m;
  float mb = merge_b[c];
#pragma unroll
  for (int r = 0; r < 4; ++r) {
    int row = rowbase + kg * 4 + r;
    out[(size_t)row * 64 + c] = acc[r] + xm[(size_t)row * 64 + c] + mb;
  }
  __syncthreads();   // gLDS reads done before next item overwrites
}

// ---------------- cooperative fused kernel ----------------
__global__ __launch_bounds__(256, 4) void k_fused(
    const float* x, const int* src, const int* dst,
    const float* W_gat, const float* attn_l, const float* attn_r,
    const float* gate_m_W, const float* gate_m_b,
    const float* gate_fn_W, const float* gate_fn_b,
    const float* merge_W, const float* merge_b, float* out,
    unsigned short* Btf, unsigned short* mWf,
    unsigned char* zq, unsigned char* featq, float* epay, float* erv,
    float* gx, float* xm,
    unsigned* staged, unsigned short* bofs,
    int* deg, unsigned short* csr_src) {
  cg::grid_group grid = cg::this_grid();
  __shared__ FusedLDS L;
  int tid = threadIdx.x;
  for (int it = blockIdx.x; it < PA_ITEMS; it += GRID_BLKS)
    phaseA_item(it, tid, L, W_gat, gate_m_W, merge_W, gate_fn_W, attn_l, attn_r,
                Btf, mWf, zq, epay, featq, src, dst, staged, bofs);
  grid.sync();
  for (int it = blockIdx.x; it < PB_ITEMS; it += GRID_BLKS)
    phaseB_item(it, tid, L, x, Btf, gate_m_b, featq, zq, xm, gx, epay, erv,
                staged, bofs, deg, csr_src);
  grid.sync();
  for (int it = blockIdx.x; it < PC_ITEMS; it += GRID_BLKS)
    phaseC_block(it, tid, L, zq, featq, epay, erv, gx, deg, csr_src,
                 gate_fn_W, gate_fn_b, mWf, xm, merge_b, out);
}

// ---------------- fallback plain-dispatch wrappers ----------------
__global__ __launch_bounds__(256, 4) void k_pA(
    const float* W_gat, const float* gate_m_W, const float* merge_W,
    const float* gate_fn_W, const float* attn_l, const float* attn_r,
    unsigned short* Btf, unsigned short* mWf, unsigned char* zq, float* epay,
    unsigned char* featq, const int* src, const int* dst,
    unsigned* staged, unsigned short* bofs) {
  __shared__ FusedLDS L;
  phaseA_item(blockIdx.x, threadIdx.x, L, W_gat, gate_m_W, merge_W, gate_fn_W,
              attn_l, attn_r, Btf, mWf, zq, epay, featq, src, dst, staged, bofs);
}
__global__ __launch_bounds__(256, 4) void k_pB(
    const float* x, const unsigned short* Btf, const float* gate_m_b,
    unsigned char* featq, unsigned char* zq, float* xm, float* gx, float* epay,
    float* erv, const unsigned* staged, const unsigned short* bofs,
    int* deg, unsigned short* csr_src) {
  __shared__ FusedLDS L;
  phaseB_item(blockIdx.x, threadIdx.x, L, x, Btf, gate_m_b, featq, zq, xm, gx,
              epay, erv, staged, bofs, deg, csr_src);
}
__global__ __launch_bounds__(256, 4) void k_pC(
    const unsigned char* zq, const unsigned char* featq, const float* epay,
    const float* er, const float* gx, const int* deg,
    const unsigned short* csr_src, const float* gate_fn_W,
    const float* gate_fn_b, const unsigned short* mWf, const float* xm,
    const float* merge_b, float* out) {
  __shared__ FusedLDS L;
  phaseC_block(blockIdx.x, threadIdx.x, L, zq, featq, epay, er, gx, deg, csr_src,
               gate_fn_W, gate_fn_b, mWf, xm, merge_b, out);
}

extern "C" void kernel_launch(void* const* d_in, const int* in_sizes, int n_in,
                              void* d_out, int out_size, void* d_ws, size_t ws_size,
                              hipStream_t stream) {
  const float* x         = (const float*)d_in[0];
  const int*   src       = (const int*)d_in[1];
  const int*   dst       = (const int*)d_in[2];
  const float* W_gat     = (const float*)d_in[3];
  const float* attn_l    = (const float*)d_in[4];
  const float* attn_r    = (const float*)d_in[5];
  const float* gate_m_W  = (const float*)d_in[6];
  const float* gate_m_b  = (const float*)d_in[7];
  const float* gate_fn_W = (const float*)d_in[8];
  const float* gate_fn_b = (const float*)d_in[9];
  const float* merge_W   = (const float*)d_in[10];
  const float* merge_b   = (const float*)d_in[11];
  float* out = (float*)d_out;

  char* ws = (char*)d_ws;
  size_t off = 0;
  auto alloc = [&](size_t bytes) -> void* {
    off = (off + 255) & ~(size_t)255;
    void* p = ws + off;
    off += bytes;
    return p;
  };
  int* deg       = (int*)alloc((size_t)NN * 4);
  unsigned short* csr_src = (unsigned short*)alloc((size_t)NN * CAP * 2);
  unsigned int* staged    = (unsigned int*)alloc((size_t)NE * 4);
  unsigned short* bofs    = (unsigned short*)alloc((size_t)NB1 * (NBUCK + 1) * 2);
  float* epay = (float*)alloc((size_t)(NN + 1) * 8 * 4);
  float* er   = (float*)alloc((size_t)NN * 4 * 4);
  float* gx   = (float*)alloc((size_t)NN * 4 * 4);
  float* xm   = (float*)alloc((size_t)NN * 64 * 4);
  unsigned char* zq    = (unsigned char*)alloc((size_t)(NN + 1) * 64);
  unsigned char* featq = (unsigned char*)alloc((size_t)(NN + 1) * 256);
  unsigned short* Btf    = (unsigned short*)alloc((size_t)NBT * 8 * 2);
  unsigned short* mWf    = (unsigned short*)alloc((size_t)512 * 8 * 2);

  static int coop = -1;
  if (coop < 0) {
    int v = 0;
    hipDeviceGetAttribute(&v, hipDeviceAttributeCooperativeLaunch, 0);
    coop = v;
  }

  if (coop) {
    void* args[] = {
      (void*)&x, (void*)&src, (void*)&dst, (void*)&W_gat, (void*)&attn_l,
      (void*)&attn_r, (void*)&gate_m_W, (void*)&gate_m_b, (void*)&gate_fn_W,
      (void*)&gate_fn_b, (void*)&merge_W, (void*)&merge_b, (void*)&out,
      (void*)&Btf, (void*)&mWf, (void*)&zq, (void*)&featq, (void*)&epay,
      (void*)&er, (void*)&gx, (void*)&xm, (void*)&staged, (void*)&bofs,
      (void*)&deg, (void*)&csr_src };
    hipError_t rc = hipLaunchCooperativeKernel((const void*)k_fused,
                                               dim3(GRID_BLKS), dim3(256),
                                               args, 0, stream);
    if (rc == hipSuccess) return;
    coop = 0;   // fall through to plain dispatches
  }

  k_pA<<<PA_ITEMS, 256, 0, stream>>>(W_gat, gate_m_W, merge_W, gate_fn_W,
                                     attn_l, attn_r, Btf, mWf, zq, epay,
                                     featq, src, dst, staged, bofs);
  k_pB<<<PB_ITEMS, 256, 0, stream>>>(x, Btf, gate_m_b, featq, zq, xm, gx,
                                     epay, er, staged, bofs, deg, csr_src);
  k_pC<<<PC_ITEMS, 256, 0, stream>>>(zq, featq, epay, er, gx, deg, csr_src,
                                     gate_fn_W, gate_fn_b, mWf, xm, merge_b, out);
}